// Round 19
// baseline (173.164 us; speedup 1.0000x reference)
//
#include <hip/hip_runtime.h>
#include <type_traits>

// MD-GRU (4-direction 2D GRU), block-resident wavefront scan, v19.
// = v18 (fp8 operands, Bc=2, 256 blocks x 8 waves, per-mt windows, packed-f32
// epilogue) with MAX-ILP restructuring. r18's clean result (VALUBusy 45->39%
// with ZERO time change) proves the step is dependency-latency-bound, not
// throughput-bound. v18 had only 3 independent MFMA chains (p-gates) per
// sequential tile -> ~10 cyc stall per MFMA. v19:
//  - ks-outer MFMA: all 4 tiles x 3 gates = 12 independent chains,
//    unconditional (inactive tiles' acc is garbage, never stored).
//  - epilogue: all 4 tiles' gate math in one unguarded block (4 independent
//    trans chains interleave); only LDS/hp/finals writes guarded by gm[mt]
//    (wave-uniform), preserving the zero-slot invariant.
// Workspace: [0,393216) U^T fp8 [a][n(384)][kk(256)]; then finals f32 [a][b][hh].

#define B_ 128
#define N_ 32
#define H_ 128
#define TH 384
#define KK 256

#define PLSTR 2640    // plane stride: 66 rows * 40 B (rows 0,1 = zeros)
#define BUFSTR 10560  // 4 planes (k-groups of 32)
#define XD_STEP 256   // 32 cells * float2

typedef float f32x4 __attribute__((ext_vector_type(4)));
typedef float f32x2 __attribute__((ext_vector_type(2)));

__device__ inline unsigned cvt2fp8(float a, float b) {  // {e4m3(a), e4m3(b)}
    return (unsigned)__builtin_amdgcn_cvt_pk_fp8_f32(a, b, 0, false);
}

#define NL2E -1.44269504088896f

// ---- U1,U2 (f32, [a][k][n]) -> U^T fp8 [a][n][kk], kk = mat*128 + k ----
__global__ void conv_u(const float* __restrict__ U1, const float* __restrict__ U2,
                       char* __restrict__ ub8) {
    __shared__ float t[32][33];
    int bx = blockIdx.x;
    int amat = bx / 48, tile = bx % 48;
    int kt = tile / 12, ntl = tile % 12;
    int a = amat >> 1, mat = amat & 1;
    int kk0 = kt * 32, n0 = ntl * 32;
    int tx = threadIdx.x, ty = threadIdx.y;
    const float* U = mat ? U2 : U1;
#pragma unroll
    for (int r = 0; r < 4; r++)
        t[ty + r * 8][tx] = U[(a * H_ + kk0 + ty + r * 8) * TH + n0 + tx];
    __syncthreads();
#pragma unroll
    for (int r = 0; r < 4; r++) {
        int n = n0 + ty + r * 8;
        int kkl = kk0 + tx;
        unsigned pk = cvt2fp8(t[tx][ty + r * 8], 0.0f);
        ub8[(a * TH + n) * KK + mat * H_ + kkl] = (char)(pk & 0xFF);
    }
}

// ---- persistent block-resident scan: 256 blocks x 512 threads (8 waves) ----
__global__ __launch_bounds__(512, 2) void scan_all(
    const float* __restrict__ x, const float* __restrict__ Wx,
    const float* __restrict__ bvec, const char* __restrict__ ubf8,
    float* __restrict__ finals) {

    __shared__ __align__(16) char hbf_c[2 * BUFSTR];     // 21120 B
    __shared__ __align__(16) char xd_c[63 * XD_STEP];    // 16128 B

    int bx = blockIdx.x;
    int a = bx >> 6, chunk = bx & 63;
    int tid = threadIdx.x;
    int lane = tid & 63, wn = tid >> 6;  // wn in [0,8): 16 hh-cols x 3 gates
    int l16 = lane & 15, lg = lane >> 4;

    for (int idx = tid; idx < (2 * BUFSTR) / 4; idx += 512) ((unsigned*)hbf_c)[idx] = 0u;
    for (int idx = tid; idx < (63 * XD_STEP) / 4; idx += 512) ((unsigned*)xd_c)[idx] = 0u;
    __syncthreads();

    // x -> diagonal-major LDS: xd[d][cell] = {x_b0(i,d-i), x_b1(i,d-i)}
    const float* xg = x + (chunk * 2) * (N_ * N_);
    for (int cell = tid; cell < 1024; cell += 512) {
        int i = cell >> 5, j = cell & 31;
        int ri = (a & 1) ? (31 - i) : i;
        int cj = (a & 2) ? (31 - j) : j;
        float v0 = xg[ri * 32 + cj];
        float v1 = xg[1024 + ri * 32 + cj];
        *(float2*)(xd_c + (i + j) * XD_STEP + i * 8) = make_float2(v0, v1);
    }

    // persistent U^T fp8 fragments: 3 gates x 16 cols x K=256 -> 24 longs (48 AGPR)
    const char* ub = ubf8 + a * (TH * KK);
    long Bf[3][8];
#pragma unroll
    for (int p = 0; p < 3; p++) {
        int n = p * H_ + wn * 16 + l16;
#pragma unroll
        for (int ks = 0; ks < 8; ks++) {
            Bf[p][ks] = *(const long*)(ub + n * KK + ks * 32 + lg * 8);
            asm volatile("" : "+v"(Bf[p][ks]));
        }
    }

    int hh = wn * 16 + l16;
    float wxp[3], bsp[3];
    {
        float wr = Wx[a * TH + hh], br = bvec[a * TH + hh];
        float wz = Wx[a * TH + H_ + hh], bz = bvec[a * TH + H_ + hh];
        float wq = Wx[a * TH + 2 * H_ + hh], bq = bvec[a * TH + 2 * H_ + hh];
        wxp[0] = wr * NL2E; bsp[0] = br * NL2E;
        wxp[1] = wz * NL2E; bsp[1] = bz * NL2E;
        wxp[2] = wq;        bsp[2] = bq;
    }

    // loop-invariant LDS addresses.
    // A matrix-row m = mt*16 + l16 <-> (cell = mt*8 + l16>>1, bl = l16&1).
    // Top-pred h(cell-1,bl) at LDS row m (= cell*2+bl); left-pred at +80 B.
    int aT[4], wbs[4];
#pragma unroll
    for (int mt = 0; mt < 4; mt++) {
        aT[mt] = (mt * 16 + l16) * 40 + lg * 8;
        wbs[mt] = (wn >> 1) * PLSTR + ((mt * 8 + lg * 2 + 1) * 2) * 40 +
                  (wn & 1) * 16 + l16;
    }

    const char* xdp = xd_c + lg * 16;
    __syncthreads();

    float hp[4][2][2];  // [mt][p2][bl] latest h of cell mt*8+lg*2+p2, batch bl
#pragma unroll
    for (int mt = 0; mt < 4; mt++)
#pragma unroll
        for (int p2 = 0; p2 < 2; p2++)
#pragma unroll
            for (int bl = 0; bl < 2; bl++) hp[mt][p2][bl] = 0.0f;

    int slsrc = (lane - 16) & 63;

    auto step = [&](int d, auto WRC) {
        constexpr int WRB = decltype(WRC)::value;
        constexpr int RDB = WRB ^ 1;
        const char* hbr = hbf_c + RDB * BUFSTR;
        char* hbw = hbf_c + WRB * BUFSTR;

        bool gm[4];
        f32x4 xv[4];
#pragma unroll
        for (int mt = 0; mt < 4; mt++) {
            gm[mt] = (d >= mt * 8) && (d <= mt * 8 + 38);  // wave-uniform window
            xv[mt] = *(const f32x4*)(xdp + WRB * 256 + mt * 64);  // always in-bounds
        }

        // neighbor p2=1 prev-h (unconditional: 8 cheap shfls)
        float sh[4][2];
#pragma unroll
        for (int mt = 0; mt < 4; mt++)
#pragma unroll
            for (int bl = 0; bl < 2; bl++)
                sh[mt][bl] = __shfl(hp[mt][1][bl], slsrc, 64);

        // preload ALL tiles' A-fragments (64 VGPR), then ks-outer MFMA:
        // 4 tiles x 3 gates = 12 independent chains -> dep latency hidden.
        long af[4][8];
#pragma unroll
        for (int mt = 0; mt < 4; mt++)
#pragma unroll
            for (int ks = 0; ks < 4; ks++) {
                af[mt][ks] = *(const long*)(hbr + ks * PLSTR + aT[mt]);          // top
                af[mt][ks + 4] = *(const long*)(hbr + ks * PLSTR + aT[mt] + 80); // left
            }

        f32x4 acc[4][3];
        const f32x4 z4 = {0.0f, 0.0f, 0.0f, 0.0f};
#pragma unroll
        for (int ks = 0; ks < 8; ks++)
#pragma unroll
            for (int mt = 0; mt < 4; mt++)
#pragma unroll
                for (int p = 0; p < 3; p++)
                    acc[mt][p] = __builtin_amdgcn_mfma_f32_16x16x32_fp8_fp8(
                        af[mt][ks], Bf[p][ks], (ks == 0) ? z4 : acc[mt][p], 0, 0, 0);

        // epilogue: ALL tiles' gate math unguarded (4 independent trans
        // chains interleave); only writes + hp updates guarded (wave-uniform).
        f32x2 hv[4][2];
#pragma unroll
        for (int mt = 0; mt < 4; mt++) {
            f32x2 top0;
            if (mt == 0)
                top0 = lg ? (f32x2){sh[0][0], sh[0][1]} : (f32x2){0.0f, 0.0f};
            else
                top0 = lg ? (f32x2){sh[mt][0], sh[mt][1]}
                          : (f32x2){sh[mt - 1][0], sh[mt - 1][1]};
#pragma unroll
            for (int p2 = 0; p2 < 2; p2++) {
                f32x2 xb = {xv[mt][p2 * 2], xv[mt][p2 * 2 + 1]};
                f32x2 Gr = {acc[mt][0][p2 * 2], acc[mt][0][p2 * 2 + 1]};
                f32x2 Gz = {acc[mt][1][p2 * 2], acc[mt][1][p2 * 2 + 1]};
                f32x2 Gn = {acc[mt][2][p2 * 2], acc[mt][2][p2 * 2 + 1]};
                f32x2 htop = p2 ? (f32x2){hp[mt][0][0], hp[mt][0][1]} : top0;
                f32x2 hlft = {hp[mt][p2][0], hp[mt][p2][1]};
                f32x2 ar = Gr * NL2E + (xb * wxp[0] + bsp[0]);
                f32x2 rg;
                rg.x = __builtin_amdgcn_rcpf(1.0f + __builtin_amdgcn_exp2f(ar.x));
                rg.y = __builtin_amdgcn_rcpf(1.0f + __builtin_amdgcn_exp2f(ar.y));
                f32x2 az = Gz * NL2E + (xb * wxp[1] + bsp[1]);
                f32x2 ezv;
                ezv.x = __builtin_amdgcn_exp2f(az.x);
                ezv.y = __builtin_amdgcn_exp2f(az.y);
                f32x2 vn = rg * Gn + (xb * wxp[2] + bsp[2]);
                f32x2 vn2 = vn * (2.0f * NL2E);
                f32x2 env;
                env.x = __builtin_amdgcn_exp2f(vn2.x);
                env.y = __builtin_amdgcn_exp2f(vn2.y);
                f32x2 pz = ezv + 1.0f, pn = env + 1.0f;
                f32x2 pzn = pz * pn;
                f32x2 rp;
                rp.x = __builtin_amdgcn_rcpf(pzn.x);
                rp.y = __builtin_amdgcn_rcpf(pzn.y);
                f32x2 zg = rp * pn;                    // sigmoid(z-arg)
                f32x2 ng = (rp * 2.0f) * pz - 1.0f;    // tanh(vn)
                f32x2 hs = htop + hlft;
                f32x2 t = ng - hs * 0.5f;
                hv[mt][p2] = ng - zg * t;
            }
        }
#pragma unroll
        for (int mt = 0; mt < 4; mt++) {
            if (gm[mt]) {
#pragma unroll
                for (int p2 = 0; p2 < 2; p2++) {
                    unsigned pk = cvt2fp8(hv[mt][p2].x, hv[mt][p2].y);
                    char* wp = hbw + wbs[mt] + p2 * 80;
                    wp[0] = (char)(pk & 0xFF);
                    wp[40] = (char)((pk >> 8) & 0xFF);
                    hp[mt][p2][0] = hv[mt][p2].x;
                    hp[mt][p2][1] = hv[mt][p2].y;
                }
            }
        }
        __syncthreads();
    };

    for (int d = 0; d < 62; d += 2) {
        step(d, std::integral_constant<int, 0>{});
        step(d + 1, std::integral_constant<int, 1>{});
        xdp += 512;
    }
    step(62, std::integral_constant<int, 0>{});

    // terminal corner: cell 31 = mt3/p2=1 on lg==3 lanes
    if (lg == 3) {
        finals[(a * B_ + chunk * 2) * H_ + hh] = hp[3][1][0];
        finals[(a * B_ + chunk * 2 + 1) * H_ + hh] = hp[3][1][1];
    }
}

// ---- final: concat 4 terminal h's -> logits -> log_softmax ----
__global__ void classify(const float* __restrict__ fin, const float* __restrict__ Wo,
                         const float* __restrict__ bo, float* __restrict__ out) {
    int b = blockIdx.x;
    int lane = threadIdx.x;  // 64
    float acc[10];
#pragma unroll
    for (int o = 0; o < 10; o++) acc[o] = 0.0f;
#pragma unroll
    for (int kkx = 0; kkx < 8; kkx++) {
        int k = kkx * 64 + lane;
        int a = k >> 7, hh = k & 127;
        float fh = fin[(a * B_ + b) * H_ + hh];
#pragma unroll
        for (int o = 0; o < 10; o++) acc[o] += fh * Wo[k * 10 + o];
    }
    float logits[10];
#pragma unroll
    for (int o = 0; o < 10; o++) {
        float v = acc[o];
#pragma unroll
        for (int off = 32; off; off >>= 1) v += __shfl_xor(v, off, 64);
        logits[o] = v + bo[o];
    }
    float m = logits[0];
#pragma unroll
    for (int o = 1; o < 10; o++) m = fmaxf(m, logits[o]);
    float s = 0.0f;
#pragma unroll
    for (int o = 0; o < 10; o++) s += __expf(logits[o] - m);
    float lse = m + __logf(s);
    if (lane == 0) {
#pragma unroll
        for (int o = 0; o < 10; o++) out[b * 10 + o] = logits[o] - lse;
    }
}

extern "C" void kernel_launch(void* const* d_in, const int* in_sizes, int n_in,
                              void* d_out, int out_size, void* d_ws, size_t ws_size,
                              hipStream_t stream) {
    const float* x = (const float*)d_in[0];
    const float* Wx = (const float*)d_in[1];
    const float* U1 = (const float*)d_in[2];
    const float* U2 = (const float*)d_in[3];
    const float* bv = (const float*)d_in[4];
    const float* Wo = (const float*)d_in[5];
    const float* bo = (const float*)d_in[6];
    float* out = (float*)d_out;

    char* ws = (char*)d_ws;
    char* ub8 = ws;                           // 4*384*256 = 393216 B
    float* finals = (float*)(ws + 393216);    // 4*128*128*4 = 256 KB

    hipLaunchKernelGGL(conv_u, dim3(384), dim3(32, 8), 0, stream, U1, U2, ub8);
    hipLaunchKernelGGL(scan_all, dim3(256), dim3(512), 0, stream, x, Wx, bv, ub8, finals);
    hipLaunchKernelGGL(classify, dim3(128), dim3(64), 0, stream, finals, Wo, bo, out);
}

// Round 20
// 145.290 us; speedup vs baseline: 1.1919x; 1.1919x over previous
//
#include <hip/hip_runtime.h>
#include <type_traits>

// MD-GRU (4-direction 2D GRU), block-resident wavefront scan, v20 = v18 revert.
// v18 is the measured best (145.5 us). v19's max-ILP experiment regressed 18%:
// unconditional MFMA added 61% matrix-pipe work (16x16x32 throughput is ~19
// cyc/SIMD, not ~5 — MFMA-busy was already 2000 cyc of the 6000-cyc step).
// Structure: Bc=2, 256 blocks x 8 waves, fp8 e4m3 operands (register-resident
// U^T in 48 AGPR), per-mt guard windows, interleaved MFMA/EPI schedule,
// register mix term, packed-f32 epilogue, guarded shfls.
// Workspace: [0,393216) U^T fp8 [a][n(384)][kk(256)]; then finals f32 [a][b][hh].

#define B_ 128
#define N_ 32
#define H_ 128
#define TH 384
#define KK 256

#define PLSTR 2640    // plane stride: 66 rows * 40 B (rows 0,1 = zeros)
#define BUFSTR 10560  // 4 planes (k-groups of 32)
#define XD_STEP 256   // 32 cells * float2

typedef float f32x4 __attribute__((ext_vector_type(4)));
typedef float f32x2 __attribute__((ext_vector_type(2)));

__device__ inline unsigned cvt2fp8(float a, float b) {  // {e4m3(a), e4m3(b)}
    return (unsigned)__builtin_amdgcn_cvt_pk_fp8_f32(a, b, 0, false);
}

#define NL2E -1.44269504088896f

// ---- U1,U2 (f32, [a][k][n]) -> U^T fp8 [a][n][kk], kk = mat*128 + k ----
__global__ void conv_u(const float* __restrict__ U1, const float* __restrict__ U2,
                       char* __restrict__ ub8) {
    __shared__ float t[32][33];
    int bx = blockIdx.x;
    int amat = bx / 48, tile = bx % 48;
    int kt = tile / 12, ntl = tile % 12;
    int a = amat >> 1, mat = amat & 1;
    int kk0 = kt * 32, n0 = ntl * 32;
    int tx = threadIdx.x, ty = threadIdx.y;
    const float* U = mat ? U2 : U1;
#pragma unroll
    for (int r = 0; r < 4; r++)
        t[ty + r * 8][tx] = U[(a * H_ + kk0 + ty + r * 8) * TH + n0 + tx];
    __syncthreads();
#pragma unroll
    for (int r = 0; r < 4; r++) {
        int n = n0 + ty + r * 8;
        int kkl = kk0 + tx;
        unsigned pk = cvt2fp8(t[tx][ty + r * 8], 0.0f);
        ub8[(a * TH + n) * KK + mat * H_ + kkl] = (char)(pk & 0xFF);
    }
}

// ---- persistent block-resident scan: 256 blocks x 512 threads (8 waves) ----
__global__ __launch_bounds__(512, 2) void scan_all(
    const float* __restrict__ x, const float* __restrict__ Wx,
    const float* __restrict__ bvec, const char* __restrict__ ubf8,
    float* __restrict__ finals) {

    __shared__ __align__(16) char hbf_c[2 * BUFSTR];     // 21120 B
    __shared__ __align__(16) char xd_c[63 * XD_STEP];    // 16128 B

    int bx = blockIdx.x;
    int a = bx >> 6, chunk = bx & 63;
    int tid = threadIdx.x;
    int lane = tid & 63, wn = tid >> 6;  // wn in [0,8): 16 hh-cols x 3 gates
    int l16 = lane & 15, lg = lane >> 4;

    for (int idx = tid; idx < (2 * BUFSTR) / 4; idx += 512) ((unsigned*)hbf_c)[idx] = 0u;
    for (int idx = tid; idx < (63 * XD_STEP) / 4; idx += 512) ((unsigned*)xd_c)[idx] = 0u;
    __syncthreads();

    // x -> diagonal-major LDS: xd[d][cell] = {x_b0(i,d-i), x_b1(i,d-i)}
    const float* xg = x + (chunk * 2) * (N_ * N_);
    for (int cell = tid; cell < 1024; cell += 512) {
        int i = cell >> 5, j = cell & 31;
        int ri = (a & 1) ? (31 - i) : i;
        int cj = (a & 2) ? (31 - j) : j;
        float v0 = xg[ri * 32 + cj];
        float v1 = xg[1024 + ri * 32 + cj];
        *(float2*)(xd_c + (i + j) * XD_STEP + i * 8) = make_float2(v0, v1);
    }

    // persistent U^T fp8 fragments: 3 gates x 16 cols x K=256 -> 24 longs (48 AGPR)
    const char* ub = ubf8 + a * (TH * KK);
    long Bf[3][8];
#pragma unroll
    for (int p = 0; p < 3; p++) {
        int n = p * H_ + wn * 16 + l16;
#pragma unroll
        for (int ks = 0; ks < 8; ks++) {
            Bf[p][ks] = *(const long*)(ub + n * KK + ks * 32 + lg * 8);
            asm volatile("" : "+v"(Bf[p][ks]));
        }
    }

    int hh = wn * 16 + l16;
    float wxp[3], bsp[3];
    {
        float wr = Wx[a * TH + hh], br = bvec[a * TH + hh];
        float wz = Wx[a * TH + H_ + hh], bz = bvec[a * TH + H_ + hh];
        float wq = Wx[a * TH + 2 * H_ + hh], bq = bvec[a * TH + 2 * H_ + hh];
        wxp[0] = wr * NL2E; bsp[0] = br * NL2E;
        wxp[1] = wz * NL2E; bsp[1] = bz * NL2E;
        wxp[2] = wq;        bsp[2] = bq;
    }

    // loop-invariant LDS addresses.
    // A matrix-row m = mt*16 + l16 <-> (cell = mt*8 + l16>>1, bl = l16&1).
    // Top-pred h(cell-1,bl) at LDS row m (= cell*2+bl); left-pred at +80 B.
    int aT[4], wbs[4];
#pragma unroll
    for (int mt = 0; mt < 4; mt++) {
        aT[mt] = (mt * 16 + l16) * 40 + lg * 8;
        wbs[mt] = (wn >> 1) * PLSTR + ((mt * 8 + lg * 2 + 1) * 2) * 40 +
                  (wn & 1) * 16 + l16;
    }

    const char* xdp = xd_c + lg * 16;
    __syncthreads();

    float hp[4][2][2];  // [mt][p2][bl] latest h of cell mt*8+lg*2+p2, batch bl
#pragma unroll
    for (int mt = 0; mt < 4; mt++)
#pragma unroll
        for (int p2 = 0; p2 < 2; p2++)
#pragma unroll
            for (int bl = 0; bl < 2; bl++) hp[mt][p2][bl] = 0.0f;

    int slsrc = (lane - 16) & 63;

    auto step = [&](int d, auto WRC) {
        constexpr int WRB = decltype(WRC)::value;
        constexpr int RDB = WRB ^ 1;
        const char* hbr = hbf_c + RDB * BUFSTR;
        char* hbw = hbf_c + WRB * BUFSTR;

        bool gm[4];
        f32x4 xv[4];
#pragma unroll
        for (int mt = 0; mt < 4; mt++) {
            gm[mt] = (d >= mt * 8) && (d <= mt * 8 + 38);  // wave-uniform window
            if (gm[mt]) xv[mt] = *(const f32x4*)(xdp + WRB * 256 + mt * 64);
        }

        // neighbor p2=1 prev-h; only when a consuming tile is in-window.
        float sh[4][2];
#pragma unroll
        for (int mt = 0; mt < 4; mt++) {
            bool need = gm[mt] || (mt < 3 && gm[mt + 1]);
            if (need) {
#pragma unroll
                for (int bl = 0; bl < 2; bl++)
                    sh[mt][bl] = __shfl(hp[mt][1][bl], slsrc, 64);
            }
        }

        f32x4 acc[4][3];
        const f32x4 z4 = {0.0f, 0.0f, 0.0f, 0.0f};

        auto do_mfma = [&](int mt) {
            long af[8];
#pragma unroll
            for (int ks = 0; ks < 4; ks++) {
                af[ks] = *(const long*)(hbr + ks * PLSTR + aT[mt]);          // top
                af[ks + 4] = *(const long*)(hbr + ks * PLSTR + aT[mt] + 80); // left
            }
#pragma unroll
            for (int ks = 0; ks < 4; ks++)
#pragma unroll
                for (int p = 0; p < 3; p++)
                    acc[mt][p] = __builtin_amdgcn_mfma_f32_16x16x32_fp8_fp8(
                        af[ks], Bf[p][ks], (ks == 0) ? z4 : acc[mt][p], 0, 0, 0);
#pragma unroll
            for (int ks = 0; ks < 4; ks++)
#pragma unroll
                for (int p = 0; p < 3; p++)
                    acc[mt][p] = __builtin_amdgcn_mfma_f32_16x16x32_fp8_fp8(
                        af[ks + 4], Bf[p][ks + 4], acc[mt][p], 0, 0, 0);
        };

        auto do_epi = [&](int mt) {
            // top-pred vector for p2==0 rows
            f32x2 top0;
            if (mt == 0)
                top0 = lg ? (f32x2){sh[0][0], sh[0][1]} : (f32x2){0.0f, 0.0f};
            else
                top0 = lg ? (f32x2){sh[mt][0], sh[mt][1]}
                          : (f32x2){sh[mt - 1][0], sh[mt - 1][1]};
#pragma unroll
            for (int p2 = 0; p2 < 2; p2++) {
                f32x2 xb = {xv[mt][p2 * 2], xv[mt][p2 * 2 + 1]};
                f32x2 Gr = {acc[mt][0][p2 * 2], acc[mt][0][p2 * 2 + 1]};
                f32x2 Gz = {acc[mt][1][p2 * 2], acc[mt][1][p2 * 2 + 1]};
                f32x2 Gn = {acc[mt][2][p2 * 2], acc[mt][2][p2 * 2 + 1]};
                f32x2 htop = p2 ? (f32x2){hp[mt][0][0], hp[mt][0][1]} : top0;
                f32x2 hlft = {hp[mt][p2][0], hp[mt][p2][1]};
                // r-gate (serial: feeds tanh arg)
                f32x2 ar = Gr * NL2E + (xb * wxp[0] + bsp[0]);
                f32x2 rg;
                rg.x = __builtin_amdgcn_rcpf(1.0f + __builtin_amdgcn_exp2f(ar.x));
                rg.y = __builtin_amdgcn_rcpf(1.0f + __builtin_amdgcn_exp2f(ar.y));
                // z-gate + n-gate share one rcp: rp = 1/((1+ez)(1+en))
                f32x2 az = Gz * NL2E + (xb * wxp[1] + bsp[1]);
                f32x2 ezv;
                ezv.x = __builtin_amdgcn_exp2f(az.x);
                ezv.y = __builtin_amdgcn_exp2f(az.y);
                f32x2 vn = rg * Gn + (xb * wxp[2] + bsp[2]);
                f32x2 vn2 = vn * (2.0f * NL2E);
                f32x2 env;
                env.x = __builtin_amdgcn_exp2f(vn2.x);
                env.y = __builtin_amdgcn_exp2f(vn2.y);
                f32x2 pz = ezv + 1.0f, pn = env + 1.0f;
                f32x2 pzn = pz * pn;
                f32x2 rp;
                rp.x = __builtin_amdgcn_rcpf(pzn.x);
                rp.y = __builtin_amdgcn_rcpf(pzn.y);
                f32x2 zg = rp * pn;                    // sigmoid(z-arg)
                f32x2 ng = (rp * 2.0f) * pz - 1.0f;    // tanh(vn)
                f32x2 hs = htop + hlft;
                f32x2 t = ng - hs * 0.5f;
                f32x2 hv = ng - zg * t;
                unsigned pk = cvt2fp8(hv.x, hv.y);
                char* wp = hbw + wbs[mt] + p2 * 80;
                wp[0] = (char)(pk & 0xFF);
                wp[40] = (char)((pk >> 8) & 0xFF);
                hp[mt][p2][0] = hv.x;
                hp[mt][p2][1] = hv.y;
            }
        };

        // interleaved schedule: EPI(mt) overlaps MFMA(mt+1) in the other pipe
        if (gm[0]) do_mfma(0);
        if (gm[1]) do_mfma(1);
        if (gm[0]) do_epi(0);
        if (gm[2]) do_mfma(2);
        if (gm[1]) do_epi(1);
        if (gm[3]) do_mfma(3);
        if (gm[2]) do_epi(2);
        if (gm[3]) do_epi(3);

        __syncthreads();
    };

    for (int d = 0; d < 62; d += 2) {
        step(d, std::integral_constant<int, 0>{});
        step(d + 1, std::integral_constant<int, 1>{});
        xdp += 512;
    }
    step(62, std::integral_constant<int, 0>{});

    // terminal corner: cell 31 = mt3/p2=1 on lg==3 lanes
    if (lg == 3) {
        finals[(a * B_ + chunk * 2) * H_ + hh] = hp[3][1][0];
        finals[(a * B_ + chunk * 2 + 1) * H_ + hh] = hp[3][1][1];
    }
}

// ---- final: concat 4 terminal h's -> logits -> log_softmax ----
__global__ void classify(const float* __restrict__ fin, const float* __restrict__ Wo,
                         const float* __restrict__ bo, float* __restrict__ out) {
    int b = blockIdx.x;
    int lane = threadIdx.x;  // 64
    float acc[10];
#pragma unroll
    for (int o = 0; o < 10; o++) acc[o] = 0.0f;
#pragma unroll
    for (int kkx = 0; kkx < 8; kkx++) {
        int k = kkx * 64 + lane;
        int a = k >> 7, hh = k & 127;
        float fh = fin[(a * B_ + b) * H_ + hh];
#pragma unroll
        for (int o = 0; o < 10; o++) acc[o] += fh * Wo[k * 10 + o];
    }
    float logits[10];
#pragma unroll
    for (int o = 0; o < 10; o++) {
        float v = acc[o];
#pragma unroll
        for (int off = 32; off; off >>= 1) v += __shfl_xor(v, off, 64);
        logits[o] = v + bo[o];
    }
    float m = logits[0];
#pragma unroll
    for (int o = 1; o < 10; o++) m = fmaxf(m, logits[o]);
    float s = 0.0f;
#pragma unroll
    for (int o = 0; o < 10; o++) s += __expf(logits[o] - m);
    float lse = m + __logf(s);
    if (lane == 0) {
#pragma unroll
        for (int o = 0; o < 10; o++) out[b * 10 + o] = logits[o] - lse;
    }
}

extern "C" void kernel_launch(void* const* d_in, const int* in_sizes, int n_in,
                              void* d_out, int out_size, void* d_ws, size_t ws_size,
                              hipStream_t stream) {
    const float* x = (const float*)d_in[0];
    const float* Wx = (const float*)d_in[1];
    const float* U1 = (const float*)d_in[2];
    const float* U2 = (const float*)d_in[3];
    const float* bv = (const float*)d_in[4];
    const float* Wo = (const float*)d_in[5];
    const float* bo = (const float*)d_in[6];
    float* out = (float*)d_out;

    char* ws = (char*)d_ws;
    char* ub8 = ws;                           // 4*384*256 = 393216 B
    float* finals = (float*)(ws + 393216);    // 4*128*128*4 = 256 KB

    hipLaunchKernelGGL(conv_u, dim3(384), dim3(32, 8), 0, stream, U1, U2, ub8);
    hipLaunchKernelGGL(scan_all, dim3(256), dim3(512), 0, stream, x, Wx, bv, ub8, finals);
    hipLaunchKernelGGL(classify, dim3(128), dim3(64), 0, stream, finals, Wo, bo, out);
}